// Round 1
// baseline (660.408 us; speedup 1.0000x reference)
//
#include <hip/hip_runtime.h>
#include <math.h>

#define N_BATCH 1000000
#define FEAT 128
#define FEAT4 32          // FEAT / 4
#define GRID_MAIN 2048
#define BLOCK_MAIN 256
#define GROUPS_PER_BLOCK 8   // 256 threads / 32 lanes-per-row

// Kernel 0: compute margin = ||c0 - c1|| / 10, zero the double accumulator.
__global__ void nh_precompute(const float* __restrict__ centers,
                              double* __restrict__ acc,
                              float* __restrict__ margin_out) {
    int lane = threadIdx.x;          // one wave of 64
    float s = 0.0f;
    for (int k = lane; k < FEAT; k += 64) {
        float d = centers[k] - centers[FEAT + k];
        s += d * d;
    }
    #pragma unroll
    for (int m = 32; m >= 1; m >>= 1) s += __shfl_xor(s, m);
    if (lane == 0) {
        *acc = 0.0;
        *margin_out = sqrtf(s) * 0.1f;
    }
}

// Main kernel: half-wave (32 lanes) per row. Wave reads 1 KB contiguous.
__global__ __launch_bounds__(BLOCK_MAIN)
void nh_main(const float4* __restrict__ x,
             const int* __restrict__ labels,
             const float4* __restrict__ centers,
             const float* __restrict__ margin_p,
             double* __restrict__ acc) {
    const float margin = *margin_p;
    const int lane32 = threadIdx.x & 31;
    const int group  = threadIdx.x >> 5;                  // 0..7
    const int stride = GRID_MAIN * GROUPS_PER_BLOCK;      // rows per grid pass

    float local = 0.0f;
    for (int row = blockIdx.x * GROUPS_PER_BLOCK + group; row < N_BATCH; row += stride) {
        const int lbl = labels[row];                       // HW same-address broadcast
        const float4 xv = x[(size_t)row * FEAT4 + lane32];
        const float4 cv = centers[(size_t)lbl * FEAT4 + lane32];
        float dx = xv.x - cv.x;
        float s  = dx * dx;
        dx = xv.y - cv.y; s = fmaf(dx, dx, s);
        dx = xv.z - cv.z; s = fmaf(dx, dx, s);
        dx = xv.w - cv.w; s = fmaf(dx, dx, s);
        // reduce the 32-lane group -> every lane in group holds row distance
        s += __shfl_xor(s, 16);
        s += __shfl_xor(s, 8);
        s += __shfl_xor(s, 4);
        s += __shfl_xor(s, 2);
        s += __shfl_xor(s, 1);
        if (lane32 == 0) {
            float h = s - margin;
            local += (h > 0.0f) ? h : 0.0f;
        }
    }

    // block reduction: full-wave shuffle, then LDS across the 4 waves
    #pragma unroll
    for (int m = 32; m >= 1; m >>= 1) local += __shfl_xor(local, m);
    __shared__ float wavesum[BLOCK_MAIN / 64];
    const int wid = threadIdx.x >> 6;
    if ((threadIdx.x & 63) == 0) wavesum[wid] = local;
    __syncthreads();
    if (threadIdx.x == 0) {
        float t = 0.0f;
        #pragma unroll
        for (int w = 0; w < BLOCK_MAIN / 64; ++w) t += wavesum[w];
        atomicAdd(acc, (double)t);
    }
}

// Final: scale and write scalar output.
__global__ void nh_finalize(const double* __restrict__ acc, float* __restrict__ out) {
    out[0] = (float)(*acc * (1.0 / ((double)N_BATCH * 4.0)));
}

extern "C" void kernel_launch(void* const* d_in, const int* in_sizes, int n_in,
                              void* d_out, int out_size, void* d_ws, size_t ws_size,
                              hipStream_t stream) {
    const float* x       = (const float*)d_in[0];   // (1e6, 128) fp32
    const int*   labels  = (const int*)d_in[1];     // (1e6,) int32
    const float* centers = (const float*)d_in[2];   // (1000, 128) fp32
    float* out = (float*)d_out;

    // ws layout: [0..7] double accumulator, [8..11] float margin
    double* acc    = (double*)d_ws;
    float*  margin = (float*)((char*)d_ws + 8);

    nh_precompute<<<1, 64, 0, stream>>>(centers, acc, margin);
    nh_main<<<GRID_MAIN, BLOCK_MAIN, 0, stream>>>(
        (const float4*)x, labels, (const float4*)centers, margin, acc);
    nh_finalize<<<1, 1, 0, stream>>>(acc, out);
}

// Round 2
// 655.084 us; speedup vs baseline: 1.0081x; 1.0081x over previous
//
#include <hip/hip_runtime.h>
#include <math.h>

#define N_BATCH 1000000
#define FEAT 128
#define FEAT4 32          // FEAT / 4
#define GRID_MAIN 2048
#define BLOCK_MAIN 256
#define GROUPS_PER_BLOCK 8   // 256 threads / 32 lanes-per-row
#define ROW_STRIDE (GRID_MAIN * GROUPS_PER_BLOCK)   // 16384

// ws layout: [0..3] float margin, [16 ..) float partials[GRID_MAIN]

// Kernel 0: margin = ||c0 - c1|| / 10.
__global__ void nh_precompute(const float* __restrict__ centers,
                              float* __restrict__ margin_out) {
    int lane = threadIdx.x;          // one wave of 64
    float s = 0.0f;
    for (int k = lane; k < FEAT; k += 64) {
        float d = centers[k] - centers[FEAT + k];
        s += d * d;
    }
    #pragma unroll
    for (int m = 32; m >= 1; m >>= 1) s += __shfl_xor(s, m);
    if (lane == 0) {
        *margin_out = sqrtf(s) * 0.1f;
    }
}

// Main kernel: half-wave (32 lanes) per row, 2 rows per iteration for ILP.
// No atomics: each block writes its partial sum to partials[blockIdx.x].
__global__ __launch_bounds__(BLOCK_MAIN)
void nh_main(const float4* __restrict__ x,
             const int* __restrict__ labels,
             const float4* __restrict__ centers,
             const float* __restrict__ margin_p,
             float* __restrict__ partials) {
    const float margin = *margin_p;
    const int lane32 = threadIdx.x & 31;
    const int group  = threadIdx.x >> 5;                  // 0..7

    float local = 0.0f;
    int row = blockIdx.x * GROUPS_PER_BLOCK + group;

    // unroll-2: two independent rows in flight per iteration
    for (; row + ROW_STRIDE < N_BATCH; row += 2 * ROW_STRIDE) {
        const int r1 = row + ROW_STRIDE;
        const int l0 = labels[row];
        const int l1 = labels[r1];
        const float4 xv0 = x[(size_t)row * FEAT4 + lane32];
        const float4 xv1 = x[(size_t)r1  * FEAT4 + lane32];
        const float4 cv0 = centers[(size_t)l0 * FEAT4 + lane32];
        const float4 cv1 = centers[(size_t)l1 * FEAT4 + lane32];

        float d0 = xv0.x - cv0.x; float s0 = d0 * d0;
        float d1 = xv1.x - cv1.x; float s1 = d1 * d1;
        d0 = xv0.y - cv0.y; s0 = fmaf(d0, d0, s0);
        d1 = xv1.y - cv1.y; s1 = fmaf(d1, d1, s1);
        d0 = xv0.z - cv0.z; s0 = fmaf(d0, d0, s0);
        d1 = xv1.z - cv1.z; s1 = fmaf(d1, d1, s1);
        d0 = xv0.w - cv0.w; s0 = fmaf(d0, d0, s0);
        d1 = xv1.w - cv1.w; s1 = fmaf(d1, d1, s1);

        // two interleaved 32-lane reductions (xor masks <32 stay in half-wave)
        #pragma unroll
        for (int m = 16; m >= 1; m >>= 1) {
            s0 += __shfl_xor(s0, m);
            s1 += __shfl_xor(s1, m);
        }
        if (lane32 == 0) {
            float h0 = s0 - margin; local += (h0 > 0.0f) ? h0 : 0.0f;
            float h1 = s1 - margin; local += (h1 > 0.0f) ? h1 : 0.0f;
        }
    }
    // tail: at most one row left for this group
    if (row < N_BATCH) {
        const int l0 = labels[row];
        const float4 xv0 = x[(size_t)row * FEAT4 + lane32];
        const float4 cv0 = centers[(size_t)l0 * FEAT4 + lane32];
        float d0 = xv0.x - cv0.x; float s0 = d0 * d0;
        d0 = xv0.y - cv0.y; s0 = fmaf(d0, d0, s0);
        d0 = xv0.z - cv0.z; s0 = fmaf(d0, d0, s0);
        d0 = xv0.w - cv0.w; s0 = fmaf(d0, d0, s0);
        #pragma unroll
        for (int m = 16; m >= 1; m >>= 1) s0 += __shfl_xor(s0, m);
        if (lane32 == 0) {
            float h0 = s0 - margin; local += (h0 > 0.0f) ? h0 : 0.0f;
        }
    }

    // block reduction: full-wave shuffle (non-lane0 hold 0), then LDS across waves
    #pragma unroll
    for (int m = 32; m >= 1; m >>= 1) local += __shfl_xor(local, m);
    __shared__ float wavesum[BLOCK_MAIN / 64];
    const int wid = threadIdx.x >> 6;
    if ((threadIdx.x & 63) == 0) wavesum[wid] = local;
    __syncthreads();
    if (threadIdx.x == 0) {
        float t = 0.0f;
        #pragma unroll
        for (int w = 0; w < BLOCK_MAIN / 64; ++w) t += wavesum[w];
        partials[blockIdx.x] = t;    // plain store, no atomic
    }
}

// Final: one block reduces GRID_MAIN partials, scales, writes scalar output.
__global__ __launch_bounds__(256)
void nh_finalize(const float* __restrict__ partials, float* __restrict__ out) {
    float s = 0.0f;
    for (int i = threadIdx.x; i < GRID_MAIN; i += 256) s += partials[i];
    #pragma unroll
    for (int m = 32; m >= 1; m >>= 1) s += __shfl_xor(s, m);
    __shared__ float wavesum[4];
    const int wid = threadIdx.x >> 6;
    if ((threadIdx.x & 63) == 0) wavesum[wid] = s;
    __syncthreads();
    if (threadIdx.x == 0) {
        float t = wavesum[0] + wavesum[1] + wavesum[2] + wavesum[3];
        out[0] = t * (1.0f / ((float)N_BATCH * 4.0f));
    }
}

extern "C" void kernel_launch(void* const* d_in, const int* in_sizes, int n_in,
                              void* d_out, int out_size, void* d_ws, size_t ws_size,
                              hipStream_t stream) {
    const float* x       = (const float*)d_in[0];   // (1e6, 128) fp32
    const int*   labels  = (const int*)d_in[1];     // (1e6,) int32
    const float* centers = (const float*)d_in[2];   // (1000, 128) fp32
    float* out = (float*)d_out;

    float* margin   = (float*)d_ws;
    float* partials = (float*)((char*)d_ws + 16);

    nh_precompute<<<1, 64, 0, stream>>>(centers, margin);
    nh_main<<<GRID_MAIN, BLOCK_MAIN, 0, stream>>>(
        (const float4*)x, labels, (const float4*)centers, margin, partials);
    nh_finalize<<<1, 256, 0, stream>>>(partials, out);
}